// Round 6
// baseline (276.278 us; speedup 1.0000x reference)
//
#include <hip/hip_runtime.h>
#include <math.h>

#define D 64
#define K 512
#define ROWS 131072       // 32*64*64
#define NELEM (ROWS * D)  // 8388608
#define NBLOCKS 1024      // ROWS / 128 rows per block
#define TGAP_ACC 640.0f   // flag threshold in acc units (packing 511 + cert ~15)
#define FLAGBIT (1 << 30)

typedef _Float16 half8 __attribute__((ext_vector_type(8)));
typedef float floatx4 __attribute__((ext_vector_type(4)));

// ws layout (bytes):
//   [0,8)            double loss accumulator   (zeroed by vq_setup)
//   [8,12)           int done-block counter    (zeroed by vq_setup)
//   [4096,6144)      float Bneg[512] = -0.5 * colnorm * 2^20 (numpy order)
//   [8192,73728)     _Float16 gH[32768]  hi B-fragments (scale 2^12)
//   [73728,139264)   _Float16 gL[32768]  lo B-fragments (scale 2^12 residual)

// ---------------------------------------------------------------------------
// Setup: codebook -> fp16 hi/lo B-fragments + scaled norms + zero counters.
// frag: half index = (((n>>4)*2 + (k>>5))*64 + ((k>>3)&3)*16 + (n&15))*8 + (k&7)
// ---------------------------------------------------------------------------
__global__ __launch_bounds__(512) void vq_setup(const float* __restrict__ cb,
                                                _Float16* __restrict__ gH,
                                                _Float16* __restrict__ gL,
                                                float* __restrict__ Bneg,
                                                double* __restrict__ loss,
                                                int* __restrict__ done) {
    int idx = blockIdx.x * 512 + threadIdx.x;   // 64 blocks x 512 = 32768
    int k = idx >> 9, n = idx & 511;
    float c = cb[idx];
    float t = c * 4096.0f;                      // 2^12, exact
    _Float16 ch = (_Float16)t;
    float r = t - (float)ch;                    // exact residual
    _Float16 cl = (_Float16)r;                  // same 2^12 scale (fp16-normal range)
    int off = (((n >> 4) * 2 + (k >> 5)) * 64 + ((k >> 3) & 3) * 16 + (n & 15)) * 8 + (k & 7);
    gH[off] = ch;
    gL[off] = cl;
    if (blockIdx.x == 0) {
#pragma clang fp contract(off)
        int j = threadIdx.x;
        float b = 0.f;
        for (int kk = 0; kk < D; ++kk) { float cc = cb[kk * K + j]; b = b + cc * cc; }
        Bneg[j] = b * -0x1p19f;                 // -B/2 * 2^20, exact pow-2 scale
        if (j == 0) { *loss = 0.0; *done = 0; }
    }
}

// ---------------------------------------------------------------------------
// Exact numpy-order rescore of one row (bitwise-identical to the R2-verified
// scalar pipeline). Lane handles 8 columns j = lane + 64m.
// ---------------------------------------------------------------------------
__device__ __noinline__ void exact_row(int row, const float* __restrict__ x,
                                       const float* __restrict__ cb,
                                       const float* bn, int lane,
                                       float* __restrict__ out, float& lsum) {
#pragma clang fp contract(off)
    const float* xr = x + (size_t)row * D;
    // A = np.sum(x**2, axis=1): pairwise n=64 emulation
    float A0;
    {
        float rr[8];
        #pragma unroll
        for (int l = 0; l < 8; ++l) rr[l] = xr[l] * xr[l];
        #pragma unroll
        for (int m = 1; m < 8; ++m)
            #pragma unroll
            for (int l = 0; l < 8; ++l) {
                float q = xr[8 * m + l] * xr[8 * m + l];
                rr[l] = rr[l] + q;
            }
        A0 = ((rr[0] + rr[1]) + (rr[2] + rr[3])) + ((rr[4] + rr[5]) + (rr[6] + rr[7]));
    }
    float a[8];
    #pragma unroll
    for (int m = 0; m < 8; ++m) a[m] = 0.f;
    for (int k = 0; k < D; ++k) {
        float xk = xr[k];
        const float* crow = cb + k * K + lane;
        #pragma unroll
        for (int m = 0; m < 8; ++m)
            a[m] = fmaf(xk, crow[m * 64], a[m]);   // sequential-k fma chain
    }
    float db = INFINITY; int jb = 0x7fffffff;
    #pragma unroll
    for (int m = 0; m < 8; ++m) {
        float s = A0 + bn[m];
        float t2 = 2.0f * a[m];
        float d = s - t2;                  // fl(fl(A+B) - fl(2M))
        int j = lane + (m << 6);
        if (d < db) { db = d; jb = j; }
    }
    for (int s = 1; s < 64; s <<= 1) {     // first-index global argmin
        float od = __shfl_xor(db, s);
        int oj = __shfl_xor(jb, s);
        if ((od < db) || (od == db && oj < jb)) { db = od; jb = oj; }
    }
    float q = cb[lane * K + jb];
    out[(size_t)row * D + lane] = q;
    float e = q - xr[lane];
    lsum += e * e;
}

// ---------------------------------------------------------------------------
// Main: MFMA filter (32 rows/wave, 4 waves) + in-block exact rescan of
// flagged rows + last-block loss finalize. 1024 blocks.
// ---------------------------------------------------------------------------
__global__ __launch_bounds__(256, 4) void vq_main(const float* __restrict__ x,
                                                  const float* __restrict__ cb,
                                                  const _Float16* __restrict__ gH,
                                                  const _Float16* __restrict__ gL,
                                                  const float* __restrict__ BnegG,
                                                  float* __restrict__ out,
                                                  double* __restrict__ loss_acc,
                                                  int* __restrict__ done) {
    __shared__ float ldsB[K];              // -B/2 * 2^20
    __shared__ int rowinfo[4][32];
    __shared__ unsigned int flagbits[4];   // 128 rows / 32
    __shared__ float wavesum[4];

    const int tid = threadIdx.x;
    const int lane = tid & 63;
    const int w = tid >> 6;
    const int quad = lane >> 4;
    const int nn = lane & 15;

    ldsB[tid] = BnegG[tid];
    ldsB[tid + 256] = BnegG[tid + 256];
    if (tid < 4) flagbits[tid] = 0;

    const int rowBase = blockIdx.x * 128 + w * 32;

    // A-fragments: lane holds A[m=nn][k=quad*8+j]; hi scale 2^8, lo residual 2^8
    half8 xh[2][2], xl[2][2];
    #pragma unroll
    for (int tt = 0; tt < 2; ++tt) {
        #pragma unroll
        for (int s = 0; s < 2; ++s) {
            const float* xp = x + (size_t)(rowBase + tt * 16 + nn) * D + s * 32 + quad * 8;
            float4 v0 = *(const float4*)xp;
            float4 v1 = *(const float4*)(xp + 4);
            float vv[8] = {v0.x, v0.y, v0.z, v0.w, v1.x, v1.y, v1.z, v1.w};
            #pragma unroll
            for (int j = 0; j < 8; ++j) {
                float t = vv[j] * 256.0f;        // 2^8, exact
                _Float16 h = (_Float16)t;
                float r = t - (float)h;          // exact residual
                xh[tt][s][j] = h;
                xl[tt][s][j] = (_Float16)r;      // same 2^8 scale
            }
        }
    }
    __syncthreads();

    // best-2 MAX trackers of acc = (M - B/2)*2^20, col packed in low 9 bits
    float M1[2][4], M2[2][4];
    #pragma unroll
    for (int tt = 0; tt < 2; ++tt)
        #pragma unroll
        for (int r = 0; r < 4; ++r) { M1[tt][r] = -INFINITY; M2[tt][r] = -INFINITY; }

    const half8* bHp = (const half8*)gH;
    const half8* bLp = (const half8*)gL;

    #pragma unroll 2
    for (int t = 0; t < 32; ++t) {
        half8 bh0 = bHp[(t * 2 + 0) * 64 + lane];   // coalesced 16B/lane
        half8 bl0 = bLp[(t * 2 + 0) * 64 + lane];
        half8 bh1 = bHp[(t * 2 + 1) * 64 + lane];
        half8 bl1 = bLp[(t * 2 + 1) * 64 + lane];
        float bneg = ldsB[t * 16 + nn];
        unsigned int colbits = (unsigned)(t * 16 + nn);
        #pragma unroll
        for (int tt = 0; tt < 2; ++tt) {
            floatx4 acc = {bneg, bneg, bneg, bneg};
            acc = __builtin_amdgcn_mfma_f32_16x16x32_f16(xh[tt][0], bh0, acc, 0, 0, 0);
            acc = __builtin_amdgcn_mfma_f32_16x16x32_f16(xl[tt][0], bh0, acc, 0, 0, 0);
            acc = __builtin_amdgcn_mfma_f32_16x16x32_f16(xh[tt][0], bl0, acc, 0, 0, 0);
            acc = __builtin_amdgcn_mfma_f32_16x16x32_f16(xh[tt][1], bh1, acc, 0, 0, 0);
            acc = __builtin_amdgcn_mfma_f32_16x16x32_f16(xl[tt][1], bh1, acc, 0, 0, 0);
            acc = __builtin_amdgcn_mfma_f32_16x16x32_f16(xh[tt][1], bl1, acc, 0, 0, 0);
            #pragma unroll
            for (int r = 0; r < 4; ++r) {
                float gq = __uint_as_float((__float_as_uint(acc[r]) & ~511u) | colbits);
                float lo = fminf(M1[tt][r], gq);
                M2[tt][r] = fmaxf(M2[tt][r], lo);
                M1[tt][r] = fmaxf(M1[tt][r], gq);
            }
        }
    }

    // merge best-2 across the 16 col-lanes (butterfly over low 4 lane bits)
    #pragma unroll
    for (int dlt = 1; dlt < 16; dlt <<= 1) {
        #pragma unroll
        for (int tt = 0; tt < 2; ++tt)
            #pragma unroll
            for (int r = 0; r < 4; ++r) {
                float o1 = __shfl_xor(M1[tt][r], dlt);
                float o2 = __shfl_xor(M2[tt][r], dlt);
                float lo = fminf(M1[tt][r], o1);
                M1[tt][r] = fmaxf(M1[tt][r], o1);
                M2[tt][r] = fmaxf(fmaxf(M2[tt][r], o2), lo);
            }
    }

    // record results; flagged rows -> LDS bits (word w is wave-owned)
    if (nn == 0) {
        #pragma unroll
        for (int tt = 0; tt < 2; ++tt)
            #pragma unroll
            for (int r = 0; r < 4; ++r) {
                int rl = tt * 16 + quad * 4 + r;               // 0..31
                int col = (int)(__float_as_uint(M1[tt][r]) & 511u);
                bool flg = (M1[tt][r] - M2[tt][r]) < TGAP_ACC;
                rowinfo[w][rl] = col | (flg ? FLAGBIT : 0);
                if (flg) atomicOr(&flagbits[w], 1u << rl);
            }
    }
    __syncthreads();

    // coalesced output + loss for certain rows
    float lsum = 0.f;
    #pragma unroll
    for (int tt = 0; tt < 2; ++tt) {
        #pragma unroll
        for (int p = 0; p < 4; ++p) {
            int rl = tt * 16 + p * 4 + quad;
            int info = rowinfo[w][rl];
            if (!(info & FLAGBIT)) {
                int j = info & 511;
                int kb = nn * 4;
                float q0 = cb[(kb + 0) * K + j];
                float q1 = cb[(kb + 1) * K + j];
                float q2 = cb[(kb + 2) * K + j];
                float q3 = cb[(kb + 3) * K + j];
                size_t row = (size_t)blockIdx.x * 128 + w * 32 + rl;
                float4 xv = *(const float4*)(x + row * D + kb);
                float e0 = q0 - xv.x, e1 = q1 - xv.y, e2 = q2 - xv.z, e3 = q3 - xv.w;
                lsum += e0 * e0 + e1 * e1 + e2 * e2 + e3 * e3;
                *(float4*)(out + row * D + kb) = make_float4(q0, q1, q2, q3);
            }
        }
    }

    // wave 0: exact rescan of this block's flagged rows (numpy-bitwise path)
    if (w == 0) {
        unsigned int any = flagbits[0] | flagbits[1] | flagbits[2] | flagbits[3];
        if (any) {
            float bn[8];    // numpy-order column norms for lane's 8 columns
            {
#pragma clang fp contract(off)
                #pragma unroll
                for (int m = 0; m < 8; ++m) bn[m] = 0.f;
                for (int k = 0; k < D; ++k) {
                    const float* crow = cb + k * K + lane;
                    #pragma unroll
                    for (int m = 0; m < 8; ++m) {
                        float c = crow[m * 64];
                        bn[m] = bn[m] + c * c;
                    }
                }
            }
            for (int wd = 0; wd < 4; ++wd) {
                unsigned int mask = flagbits[wd];
                while (mask) {
                    int b = __builtin_ctz(mask);
                    mask &= mask - 1;
                    int row = blockIdx.x * 128 + wd * 32 + b;
                    exact_row(row, x, cb, bn, lane, out, lsum);
                }
            }
        }
    }

    #pragma unroll
    for (int off = 32; off > 0; off >>= 1) lsum += __shfl_down(lsum, off);
    if (lane == 0) wavesum[w] = lsum;
    __syncthreads();
    if (tid == 0) {
        double tot = (double)wavesum[0] + (double)wavesum[1]
                   + (double)wavesum[2] + (double)wavesum[3];
        atomicAdd(loss_acc, tot);
        __threadfence();
        int old = atomicAdd(done, 1);
        if (old == NBLOCKS - 1) {       // last block finalizes the loss
            double total = atomicAdd(loss_acc, 0.0);
            out[NELEM] = (float)(total * (1.25 / (double)NELEM));
        }
    }
}

extern "C" void kernel_launch(void* const* d_in, const int* in_sizes, int n_in,
                              void* d_out, int out_size, void* d_ws, size_t ws_size,
                              hipStream_t stream) {
    const float* x  = (const float*)d_in[0];   // [32,64,64,64] fp32
    const float* cb = (const float*)d_in[1];   // [64,512] fp32
    float* out = (float*)d_out;                // [8388608] out + [1] loss
    double* loss_acc = (double*)d_ws;
    int* done        = (int*)((char*)d_ws + 8);
    float* Bneg      = (float*)((char*)d_ws + 4096);
    _Float16* gH     = (_Float16*)((char*)d_ws + 8192);
    _Float16* gL     = (_Float16*)((char*)d_ws + 73728);

    vq_setup<<<64, 512, 0, stream>>>(cb, gH, gL, Bneg, loss_acc, done);
    vq_main<<<NBLOCKS, 256, 0, stream>>>(x, cb, gH, gL, Bneg, out, loss_acc, done);
}

// Round 7
// 231.675 us; speedup vs baseline: 1.1925x; 1.1925x over previous
//
#include <hip/hip_runtime.h>
#include <math.h>

#define D 64
#define K 512
#define ROWS 131072       // 32*64*64
#define NELEM (ROWS * D)  // 8388608
#define TGAP_ACC 640.0f   // flag threshold in acc units (packing 511 + cert margin)
#define FLAGBIT (1 << 30)
#define RESCAN_BLOCKS 512

typedef _Float16 half8 __attribute__((ext_vector_type(8)));
typedef float floatx4 __attribute__((ext_vector_type(4)));

// ws layout (bytes):
//   [0,8)            double loss accumulator   (zeroed by vq_setup)
//   [8,12)           int done-block counter    (zeroed by vq_setup)
//   [4096,6144)      float Bneg[512] = -0.5 * colnorm * 2^20 (numpy order)
//   [8192,73728)     _Float16 gH[32768]  hi B-fragments (scale 2^12)
//   [73728,139264)   _Float16 gL[32768]  lo B-fragments (residual, scale 2^12)
//   [139264,155648)  uint32 bitmap[4096] flagged-row bitmap
//   [155648,286720)  float cbT[512*64]   transposed codebook (row j contiguous)

// ---------------------------------------------------------------------------
// Setup: fragments + transposed codebook + scaled norms + zero counters.
// frag: half index = (((n>>4)*2 + (k>>5))*64 + ((k>>3)&3)*16 + (n&15))*8 + (k&7)
// ---------------------------------------------------------------------------
__global__ __launch_bounds__(512) void vq_setup(const float* __restrict__ cb,
                                                _Float16* __restrict__ gH,
                                                _Float16* __restrict__ gL,
                                                float* __restrict__ Bneg,
                                                float* __restrict__ cbT,
                                                double* __restrict__ loss,
                                                int* __restrict__ done) {
    int idx = blockIdx.x * 512 + threadIdx.x;   // 64 blocks x 512 = 32768
    int k = idx >> 9, n = idx & 511;
    float c = cb[idx];
    float t = c * 4096.0f;                      // 2^12, exact
    _Float16 ch = (_Float16)t;
    float r = t - (float)ch;                    // exact residual
    _Float16 cl = (_Float16)r;                  // same 2^12 scale
    int off = (((n >> 4) * 2 + (k >> 5)) * 64 + ((k >> 3) & 3) * 16 + (n & 15)) * 8 + (k & 7);
    gH[off] = ch;
    gL[off] = cl;
    cbT[n * 64 + k] = c;                        // one-time scattered transpose
    if (blockIdx.x == 0) {
#pragma clang fp contract(off)
        int j = threadIdx.x;
        float b = 0.f;
        for (int kk = 0; kk < D; ++kk) { float cc = cb[kk * K + j]; b = b + cc * cc; }
        Bneg[j] = b * -0x1p19f;                 // -B/2 * 2^20, exact pow-2 scale
        if (j == 0) { *loss = 0.0; *done = 0; }
    }
}

// ---------------------------------------------------------------------------
// Main: MFMA filter, 4 waves x 64 rows/wave = 256 rows/block, 512 blocks.
// ---------------------------------------------------------------------------
__global__ __launch_bounds__(256, 2) void vq_main(const float* __restrict__ x,
                                                  const float* __restrict__ cbT,
                                                  const _Float16* __restrict__ gH,
                                                  const _Float16* __restrict__ gL,
                                                  const float* __restrict__ BnegG,
                                                  float* __restrict__ out,
                                                  double* __restrict__ loss_acc,
                                                  unsigned int* __restrict__ bitmap) {
    __shared__ float ldsB[K];              // -B/2 * 2^20
    __shared__ int rowinfo[4][64];
    __shared__ unsigned int flagbits[8];   // 256 rows
    __shared__ float wavesum[4];

    const int tid = threadIdx.x;
    const int lane = tid & 63;
    const int w = tid >> 6;
    const int quad = lane >> 4;
    const int nn = lane & 15;

    ldsB[tid] = BnegG[tid];
    ldsB[tid + 256] = BnegG[tid + 256];
    if (tid < 8) flagbits[tid] = 0;

    const int rowBase = blockIdx.x * 256 + w * 64;

    // A-fragments: lane holds A[m=nn][k=quad*8+j]; hi 2^8, lo residual 2^8
    half8 xh[4][2], xl[4][2];
    #pragma unroll
    for (int tt = 0; tt < 4; ++tt) {
        #pragma unroll
        for (int s = 0; s < 2; ++s) {
            const float* xp = x + (size_t)(rowBase + tt * 16 + nn) * D + s * 32 + quad * 8;
            float4 v0 = *(const float4*)xp;
            float4 v1 = *(const float4*)(xp + 4);
            float vv[8] = {v0.x, v0.y, v0.z, v0.w, v1.x, v1.y, v1.z, v1.w};
            #pragma unroll
            for (int j = 0; j < 8; ++j) {
                float t = vv[j] * 256.0f;        // 2^8, exact
                _Float16 h = (_Float16)t;
                float r = t - (float)h;          // exact residual
                xh[tt][s][j] = h;
                xl[tt][s][j] = (_Float16)r;      // same 2^8 scale
            }
        }
    }
    __syncthreads();

    // best-2 MAX trackers of acc=(M - B/2)*2^20, col packed in low 9 bits
    float M1[4][4], M2[4][4];
    #pragma unroll
    for (int tt = 0; tt < 4; ++tt)
        #pragma unroll
        for (int r = 0; r < 4; ++r) { M1[tt][r] = -INFINITY; M2[tt][r] = -INFINITY; }

    const half8* bHp = (const half8*)gH;
    const half8* bLp = (const half8*)gL;

    half8 bh0 = bHp[lane], bl0 = bLp[lane];
    half8 bh1 = bHp[64 + lane], bl1 = bLp[64 + lane];

    #pragma unroll 2
    for (int t = 0; t < 32; ++t) {
        int tn = (t + 1) & 31;                   // prefetch next K-tile (wraps, harmless)
        half8 nh0 = bHp[(tn * 2 + 0) * 64 + lane];
        half8 nl0 = bLp[(tn * 2 + 0) * 64 + lane];
        half8 nh1 = bHp[(tn * 2 + 1) * 64 + lane];
        half8 nl1 = bLp[(tn * 2 + 1) * 64 + lane];
        float bneg = ldsB[t * 16 + nn];
        unsigned int colbits = (unsigned)(t * 16 + nn);
        #pragma unroll
        for (int tt = 0; tt < 4; ++tt) {
            floatx4 acc = {bneg, bneg, bneg, bneg};
            acc = __builtin_amdgcn_mfma_f32_16x16x32_f16(xh[tt][0], bh0, acc, 0, 0, 0);
            acc = __builtin_amdgcn_mfma_f32_16x16x32_f16(xl[tt][0], bh0, acc, 0, 0, 0);
            acc = __builtin_amdgcn_mfma_f32_16x16x32_f16(xh[tt][0], bl0, acc, 0, 0, 0);
            acc = __builtin_amdgcn_mfma_f32_16x16x32_f16(xh[tt][1], bh1, acc, 0, 0, 0);
            acc = __builtin_amdgcn_mfma_f32_16x16x32_f16(xl[tt][1], bh1, acc, 0, 0, 0);
            acc = __builtin_amdgcn_mfma_f32_16x16x32_f16(xh[tt][1], bl1, acc, 0, 0, 0);
            #pragma unroll
            for (int r = 0; r < 4; ++r) {
                float gq = __uint_as_float((__float_as_uint(acc[r]) & ~511u) | colbits);
                float lo = fminf(M1[tt][r], gq);
                M2[tt][r] = fmaxf(M2[tt][r], lo);
                M1[tt][r] = fmaxf(M1[tt][r], gq);
            }
        }
        bh0 = nh0; bl0 = nl0; bh1 = nh1; bl1 = nl1;
    }

    // merge best-2 across the 16 col-lanes (butterfly over low 4 lane bits)
    #pragma unroll
    for (int dlt = 1; dlt < 16; dlt <<= 1) {
        #pragma unroll
        for (int tt = 0; tt < 4; ++tt)
            #pragma unroll
            for (int r = 0; r < 4; ++r) {
                float o1 = __shfl_xor(M1[tt][r], dlt);
                float o2 = __shfl_xor(M2[tt][r], dlt);
                float lo = fminf(M1[tt][r], o1);
                M1[tt][r] = fmaxf(M1[tt][r], o1);
                M2[tt][r] = fmaxf(fmaxf(M2[tt][r], o2), lo);
            }
    }

    // record results; flagged rows -> LDS bits (word (w*64+rl)>>5)
    if (nn == 0) {
        #pragma unroll
        for (int tt = 0; tt < 4; ++tt)
            #pragma unroll
            for (int r = 0; r < 4; ++r) {
                int rl = tt * 16 + quad * 4 + r;               // 0..63
                int col = (int)(__float_as_uint(M1[tt][r]) & 511u);
                bool flg = (M1[tt][r] - M2[tt][r]) < TGAP_ACC;
                rowinfo[w][rl] = col | (flg ? FLAGBIT : 0);
                if (flg) atomicOr(&flagbits[(w * 64 + rl) >> 5], 1u << ((w * 64 + rl) & 31));
            }
    }
    __syncthreads();
    if (tid < 8) bitmap[blockIdx.x * 8 + tid] = flagbits[tid];

    // coalesced output + loss for certain rows (cbT row-gather, 1KB/instr write)
    float lsum = 0.f;
    #pragma unroll
    for (int tt = 0; tt < 4; ++tt) {
        #pragma unroll
        for (int p = 0; p < 4; ++p) {
            int rl = tt * 16 + p * 4 + quad;
            int info = rowinfo[w][rl];
            if (!(info & FLAGBIT)) {
                int j = info & 511;
                size_t row = (size_t)rowBase + rl;
                float4 qv = *(const float4*)(cbT + j * 64 + nn * 4);
                float4 xv = *(const float4*)(x + row * D + nn * 4);
                float e0 = qv.x - xv.x, e1 = qv.y - xv.y;
                float e2 = qv.z - xv.z, e3 = qv.w - xv.w;
                lsum += e0 * e0 + e1 * e1 + e2 * e2 + e3 * e3;
                *(float4*)(out + row * D + nn * 4) = qv;
            }
        }
    }
    #pragma unroll
    for (int off = 32; off > 0; off >>= 1) lsum += __shfl_down(lsum, off);
    if (lane == 0) wavesum[w] = lsum;
    __syncthreads();
    if (tid == 0) {
        double tot = (double)wavesum[0] + (double)wavesum[1]
                   + (double)wavesum[2] + (double)wavesum[3];
        atomicAdd(loss_acc, tot);
    }
}

// ---------------------------------------------------------------------------
// Rescan: exact numpy-order pipeline for flagged rows (bitwise R2 path).
// One wave per 64-row span; lane handles 8 columns. Last block finalizes loss.
// ---------------------------------------------------------------------------
__global__ __launch_bounds__(256) void vq_rescan(const float* __restrict__ x,
                                                 const float* __restrict__ cb,
                                                 const float* __restrict__ cbT,
                                                 float* __restrict__ out,
                                                 double* __restrict__ loss_acc,
                                                 int* __restrict__ done,
                                                 const unsigned int* __restrict__ bitmap) {
#pragma clang fp contract(off)
    __shared__ float wavesum[4];
    const int tid = threadIdx.x;
    const int lane = tid & 63;
    const int w = tid >> 6;
    const int gwave = blockIdx.x * 4 + w;      // 0..2047

    unsigned int w0 = bitmap[gwave * 2 + 0];
    unsigned int w1 = bitmap[gwave * 2 + 1];
    unsigned long long mask = ((unsigned long long)w1 << 32) | w0;
    float wloss = 0.f;
    if (mask) {
        // numpy-order column norms for lane's 8 columns (hoisted)
        float bn[8];
        #pragma unroll
        for (int m = 0; m < 8; ++m) bn[m] = 0.f;
        for (int k = 0; k < D; ++k) {
            const float* crow = cb + k * K + lane;
            #pragma unroll
            for (int m = 0; m < 8; ++m) {
                float c = crow[m * 64];
                bn[m] = bn[m] + c * c;
            }
        }
        while (mask) {
            int b = __builtin_ctzll(mask);
            mask &= mask - 1;
            int row = gwave * 64 + b;
            const float* xr = x + (size_t)row * D;
            // A = np.sum(x**2, axis=1): pairwise n=64 emulation
            float A0;
            {
                float rr[8];
                #pragma unroll
                for (int l = 0; l < 8; ++l) rr[l] = xr[l] * xr[l];
                #pragma unroll
                for (int m = 1; m < 8; ++m)
                    #pragma unroll
                    for (int l = 0; l < 8; ++l) {
                        float q = xr[8 * m + l] * xr[8 * m + l];
                        rr[l] = rr[l] + q;
                    }
                A0 = ((rr[0] + rr[1]) + (rr[2] + rr[3])) + ((rr[4] + rr[5]) + (rr[6] + rr[7]));
            }
            float a[8];
            #pragma unroll
            for (int m = 0; m < 8; ++m) a[m] = 0.f;
            for (int k = 0; k < D; ++k) {
                float xk = xr[k];
                const float* crow = cb + k * K + lane;
                #pragma unroll
                for (int m = 0; m < 8; ++m)
                    a[m] = fmaf(xk, crow[m * 64], a[m]);   // sequential-k fma chain
            }
            float db = INFINITY; int jb = 0x7fffffff;
            #pragma unroll
            for (int m = 0; m < 8; ++m) {
                float s = A0 + bn[m];
                float t2 = 2.0f * a[m];
                float d = s - t2;                  // fl(fl(A+B) - fl(2M))
                int j = lane + (m << 6);
                if (d < db) { db = d; jb = j; }
            }
            for (int s = 1; s < 64; s <<= 1) {     // first-index global argmin
                float od = __shfl_xor(db, s);
                int oj = __shfl_xor(jb, s);
                if ((od < db) || (od == db && oj < jb)) { db = od; jb = oj; }
            }
            float q = cbT[jb * 64 + lane];          // coalesced row gather
            out[(size_t)row * D + lane] = q;
            float e = q - xr[lane];
            wloss += e * e;
        }
    }
    #pragma unroll
    for (int off = 32; off > 0; off >>= 1) wloss += __shfl_down(wloss, off);
    if (lane == 0) wavesum[w] = wloss;
    __syncthreads();
    if (tid == 0) {
        double tot = (double)wavesum[0] + (double)wavesum[1]
                   + (double)wavesum[2] + (double)wavesum[3];
        if (tot != 0.0) atomicAdd(loss_acc, tot);
        __threadfence();
        int old = atomicAdd(done, 1);
        if (old == RESCAN_BLOCKS - 1) {            // last block finalizes loss
            double total = atomicAdd(loss_acc, 0.0);
            out[NELEM] = (float)(total * (1.25 / (double)NELEM));
        }
    }
}

extern "C" void kernel_launch(void* const* d_in, const int* in_sizes, int n_in,
                              void* d_out, int out_size, void* d_ws, size_t ws_size,
                              hipStream_t stream) {
    const float* x  = (const float*)d_in[0];   // [32,64,64,64] fp32
    const float* cb = (const float*)d_in[1];   // [64,512] fp32
    float* out = (float*)d_out;                // [8388608] out + [1] loss
    double* loss_acc = (double*)d_ws;
    int* done        = (int*)((char*)d_ws + 8);
    float* Bneg      = (float*)((char*)d_ws + 4096);
    _Float16* gH     = (_Float16*)((char*)d_ws + 8192);
    _Float16* gL     = (_Float16*)((char*)d_ws + 73728);
    unsigned int* bm = (unsigned int*)((char*)d_ws + 139264);
    float* cbT       = (float*)((char*)d_ws + 155648);

    vq_setup<<<64, 512, 0, stream>>>(cb, gH, gL, Bneg, cbT, loss_acc, done);
    vq_main<<<512, 256, 0, stream>>>(x, cbT, gH, gL, Bneg, out, loss_acc, bm);
    vq_rescan<<<RESCAN_BLOCKS, 256, 0, stream>>>(x, cb, cbT, out, loss_acc, done, bm);
}

// Round 8
// 184.557 us; speedup vs baseline: 1.4970x; 1.2553x over previous
//
#include <hip/hip_runtime.h>
#include <math.h>

#define D 64
#define K 512
#define ROWS 131072       // 32*64*64
#define NELEM (ROWS * D)  // 8388608
#define TGAP_CERT 40.0f   // certification bound in acc units (= 7.6e-5 distance)
#define FLAGBIT (1 << 30)
#define RESCAN_BLOCKS 512

typedef _Float16 half8 __attribute__((ext_vector_type(8)));
typedef float floatx4 __attribute__((ext_vector_type(4)));

// ws layout (bytes):
//   [0,8)            double loss accumulator   (zeroed by vq_setup)
//   [8,12)           int done-block counter    (zeroed by vq_setup)
//   [4096,6144)      float Bneg[512] = -0.5 * colnorm * 2^20 (numpy order)
//   [8192,73728)     _Float16 gH[32768]  hi B-fragments (scale 2^12)
//   [73728,139264)   _Float16 gL[32768]  lo B-fragments (residual, scale 2^12)
//   [139264,155648)  uint32 bitmap[4096] flagged-row bitmap
//   [155648,286720)  float cbT[512*64]   transposed codebook (row j contiguous)

// ---------------------------------------------------------------------------
// Setup: fragments + transposed codebook + scaled norms + zero counters.
// frag: half index = (((n>>4)*2 + (k>>5))*64 + ((k>>3)&3)*16 + (n&15))*8 + (k&7)
// ---------------------------------------------------------------------------
__global__ __launch_bounds__(512) void vq_setup(const float* __restrict__ cb,
                                                _Float16* __restrict__ gH,
                                                _Float16* __restrict__ gL,
                                                float* __restrict__ Bneg,
                                                float* __restrict__ cbT,
                                                double* __restrict__ loss,
                                                int* __restrict__ done) {
    int idx = blockIdx.x * 512 + threadIdx.x;   // 64 blocks x 512 = 32768
    int k = idx >> 9, n = idx & 511;
    float c = cb[idx];
    float t = c * 4096.0f;                      // 2^12, exact
    _Float16 ch = (_Float16)t;
    float r = t - (float)ch;                    // exact residual
    _Float16 cl = (_Float16)r;                  // same 2^12 scale
    int off = (((n >> 4) * 2 + (k >> 5)) * 64 + ((k >> 3) & 3) * 16 + (n & 15)) * 8 + (k & 7);
    gH[off] = ch;
    gL[off] = cl;
    cbT[n * 64 + k] = c;                        // one-time scattered transpose
    if (blockIdx.x == 0) {
#pragma clang fp contract(off)
        int j = threadIdx.x;
        float b = 0.f;
        for (int kk = 0; kk < D; ++kk) { float cc = cb[kk * K + j]; b = b + cc * cc; }
        Bneg[j] = b * -0x1p19f;                 // -B/2 * 2^20, exact pow-2 scale
        if (j == 0) { *loss = 0.0; *done = 0; }
    }
}

// ---------------------------------------------------------------------------
// Main: MFMA filter, 4 waves x 64 rows/wave = 256 rows/block, 512 blocks.
// ---------------------------------------------------------------------------
__global__ __launch_bounds__(256, 2) void vq_main(const float* __restrict__ x,
                                                  const float* __restrict__ cbT,
                                                  const _Float16* __restrict__ gH,
                                                  const _Float16* __restrict__ gL,
                                                  const float* __restrict__ BnegG,
                                                  float* __restrict__ out,
                                                  double* __restrict__ loss_acc,
                                                  unsigned int* __restrict__ bitmap) {
    __shared__ float ldsB[K];              // -B/2 * 2^20
    __shared__ int rowinfo[4][64];
    __shared__ unsigned int flagbits[8];   // 256 rows
    __shared__ float wavesum[4];

    const int tid = threadIdx.x;
    const int lane = tid & 63;
    const int w = tid >> 6;
    const int quad = lane >> 4;
    const int nn = lane & 15;

    ldsB[tid] = BnegG[tid];
    ldsB[tid + 256] = BnegG[tid + 256];
    if (tid < 8) flagbits[tid] = 0;

    const int rowBase = blockIdx.x * 256 + w * 64;

    // A-fragments: lane holds A[m=nn][k=quad*8+j]; hi 2^8, lo residual 2^8
    half8 xh[4][2], xl[4][2];
    #pragma unroll
    for (int tt = 0; tt < 4; ++tt) {
        #pragma unroll
        for (int s = 0; s < 2; ++s) {
            const float* xp = x + (size_t)(rowBase + tt * 16 + nn) * D + s * 32 + quad * 8;
            float4 v0 = *(const float4*)xp;
            float4 v1 = *(const float4*)(xp + 4);
            float vv[8] = {v0.x, v0.y, v0.z, v0.w, v1.x, v1.y, v1.z, v1.w};
            #pragma unroll
            for (int j = 0; j < 8; ++j) {
                float t = vv[j] * 256.0f;        // 2^8, exact
                _Float16 h = (_Float16)t;
                float r = t - (float)h;          // exact residual
                xh[tt][s][j] = h;
                xl[tt][s][j] = (_Float16)r;      // same 2^8 scale
            }
        }
    }
    __syncthreads();

    // best-2 MAX trackers of acc=(M - B/2)*2^20, col packed in low 9 bits
    float M1[4][4], M2[4][4];
    #pragma unroll
    for (int tt = 0; tt < 4; ++tt)
        #pragma unroll
        for (int r = 0; r < 4; ++r) { M1[tt][r] = -INFINITY; M2[tt][r] = -INFINITY; }

    const half8* bHp = (const half8*)gH;
    const half8* bLp = (const half8*)gL;

    half8 bh0 = bHp[lane], bl0 = bLp[lane];
    half8 bh1 = bHp[64 + lane], bl1 = bLp[64 + lane];

    #pragma unroll 2
    for (int t = 0; t < 32; ++t) {
        int tn = (t + 1) & 31;                   // prefetch next K-tile (wraps, harmless)
        half8 nh0 = bHp[(tn * 2 + 0) * 64 + lane];
        half8 nl0 = bLp[(tn * 2 + 0) * 64 + lane];
        half8 nh1 = bHp[(tn * 2 + 1) * 64 + lane];
        half8 nl1 = bLp[(tn * 2 + 1) * 64 + lane];
        float bneg = ldsB[t * 16 + nn];
        unsigned int colbits = (unsigned)(t * 16 + nn);
        #pragma unroll
        for (int tt = 0; tt < 4; ++tt) {
            floatx4 acc = {bneg, bneg, bneg, bneg};
            acc = __builtin_amdgcn_mfma_f32_16x16x32_f16(xh[tt][0], bh0, acc, 0, 0, 0);
            acc = __builtin_amdgcn_mfma_f32_16x16x32_f16(xl[tt][0], bh0, acc, 0, 0, 0);
            acc = __builtin_amdgcn_mfma_f32_16x16x32_f16(xh[tt][0], bl0, acc, 0, 0, 0);
            acc = __builtin_amdgcn_mfma_f32_16x16x32_f16(xh[tt][1], bh1, acc, 0, 0, 0);
            acc = __builtin_amdgcn_mfma_f32_16x16x32_f16(xl[tt][1], bh1, acc, 0, 0, 0);
            acc = __builtin_amdgcn_mfma_f32_16x16x32_f16(xh[tt][1], bl1, acc, 0, 0, 0);
            #pragma unroll
            for (int r = 0; r < 4; ++r) {
                float gq = __uint_as_float((__float_as_uint(acc[r]) & ~511u) | colbits);
                float lo = fminf(M1[tt][r], gq);
                M2[tt][r] = fmaxf(M2[tt][r], lo);
                M1[tt][r] = fmaxf(M1[tt][r], gq);
            }
        }
        bh0 = nh0; bl0 = nl0; bh1 = nh1; bl1 = nl1;
    }

    // merge best-2 across the 16 col-lanes (butterfly over low 4 lane bits)
    #pragma unroll
    for (int dlt = 1; dlt < 16; dlt <<= 1) {
        #pragma unroll
        for (int tt = 0; tt < 4; ++tt)
            #pragma unroll
            for (int r = 0; r < 4; ++r) {
                float o1 = __shfl_xor(M1[tt][r], dlt);
                float o2 = __shfl_xor(M2[tt][r], dlt);
                float lo = fminf(M1[tt][r], o1);
                M1[tt][r] = fmaxf(M1[tt][r], o1);
                M2[tt][r] = fmaxf(fmaxf(M2[tt][r], o2), lo);
            }
    }

    // record results; flagged rows -> LDS bits.
    // Threshold = cert bound + 1022 ulp(M1): covers both candidates' 511-ulp
    // packing perturbation at M1's binade, regardless of |acc| magnitude.
    if (nn == 0) {
        #pragma unroll
        for (int tt = 0; tt < 4; ++tt)
            #pragma unroll
            for (int r = 0; r < 4; ++r) {
                int rl = tt * 16 + quad * 4 + r;               // 0..63
                int col = (int)(__float_as_uint(M1[tt][r]) & 511u);
                float ulp = __uint_as_float(__float_as_uint(M1[tt][r]) & 0x7f800000u) * 0x1p-23f;
                float thr = fmaf(1022.0f, ulp, TGAP_CERT);
                bool flg = (M1[tt][r] - M2[tt][r]) < thr;
                rowinfo[w][rl] = col | (flg ? FLAGBIT : 0);
                if (flg) atomicOr(&flagbits[(w * 64 + rl) >> 5], 1u << ((w * 64 + rl) & 31));
            }
    }
    __syncthreads();
    if (tid < 8) bitmap[blockIdx.x * 8 + tid] = flagbits[tid];

    // coalesced output + loss for certain rows (cbT row-gather, 1KB/instr write)
    float lsum = 0.f;
    #pragma unroll
    for (int tt = 0; tt < 4; ++tt) {
        #pragma unroll
        for (int p = 0; p < 4; ++p) {
            int rl = tt * 16 + p * 4 + quad;
            int info = rowinfo[w][rl];
            if (!(info & FLAGBIT)) {
                int j = info & 511;
                size_t row = (size_t)rowBase + rl;
                float4 qv = *(const float4*)(cbT + j * 64 + nn * 4);
                float4 xv = *(const float4*)(x + row * D + nn * 4);
                float e0 = qv.x - xv.x, e1 = qv.y - xv.y;
                float e2 = qv.z - xv.z, e3 = qv.w - xv.w;
                lsum += e0 * e0 + e1 * e1 + e2 * e2 + e3 * e3;
                *(float4*)(out + row * D + nn * 4) = qv;
            }
        }
    }
    #pragma unroll
    for (int off = 32; off > 0; off >>= 1) lsum += __shfl_down(lsum, off);
    if (lane == 0) wavesum[w] = lsum;
    __syncthreads();
    if (tid == 0) {
        double tot = (double)wavesum[0] + (double)wavesum[1]
                   + (double)wavesum[2] + (double)wavesum[3];
        atomicAdd(loss_acc, tot);
    }
}

// ---------------------------------------------------------------------------
// Rescan: exact numpy-order pipeline for flagged rows (bitwise R2 path).
// One wave per 64-row span; lane handles 8 columns. Last block finalizes loss.
// ---------------------------------------------------------------------------
__global__ __launch_bounds__(256) void vq_rescan(const float* __restrict__ x,
                                                 const float* __restrict__ cb,
                                                 const float* __restrict__ cbT,
                                                 float* __restrict__ out,
                                                 double* __restrict__ loss_acc,
                                                 int* __restrict__ done,
                                                 const unsigned int* __restrict__ bitmap) {
#pragma clang fp contract(off)
    __shared__ float wavesum[4];
    const int tid = threadIdx.x;
    const int lane = tid & 63;
    const int w = tid >> 6;
    const int gwave = blockIdx.x * 4 + w;      // 0..2047

    unsigned int w0 = bitmap[gwave * 2 + 0];
    unsigned int w1 = bitmap[gwave * 2 + 1];
    unsigned long long mask = ((unsigned long long)w1 << 32) | w0;
    float wloss = 0.f;
    if (mask) {
        // numpy-order column norms for lane's 8 columns (hoisted)
        float bn[8];
        #pragma unroll
        for (int m = 0; m < 8; ++m) bn[m] = 0.f;
        for (int k = 0; k < D; ++k) {
            const float* crow = cb + k * K + lane;
            #pragma unroll
            for (int m = 0; m < 8; ++m) {
                float c = crow[m * 64];
                bn[m] = bn[m] + c * c;
            }
        }
        while (mask) {
            int b = __builtin_ctzll(mask);
            mask &= mask - 1;
            int row = gwave * 64 + b;
            const float* xr = x + (size_t)row * D;
            // A = np.sum(x**2, axis=1): pairwise n=64 emulation
            float A0;
            {
                float rr[8];
                #pragma unroll
                for (int l = 0; l < 8; ++l) rr[l] = xr[l] * xr[l];
                #pragma unroll
                for (int m = 1; m < 8; ++m)
                    #pragma unroll
                    for (int l = 0; l < 8; ++l) {
                        float q = xr[8 * m + l] * xr[8 * m + l];
                        rr[l] = rr[l] + q;
                    }
                A0 = ((rr[0] + rr[1]) + (rr[2] + rr[3])) + ((rr[4] + rr[5]) + (rr[6] + rr[7]));
            }
            float a[8];
            #pragma unroll
            for (int m = 0; m < 8; ++m) a[m] = 0.f;
            for (int k = 0; k < D; ++k) {
                float xk = xr[k];
                const float* crow = cb + k * K + lane;
                #pragma unroll
                for (int m = 0; m < 8; ++m)
                    a[m] = fmaf(xk, crow[m * 64], a[m]);   // sequential-k fma chain
            }
            float db = INFINITY; int jb = 0x7fffffff;
            #pragma unroll
            for (int m = 0; m < 8; ++m) {
                float s = A0 + bn[m];
                float t2 = 2.0f * a[m];
                float d = s - t2;                  // fl(fl(A+B) - fl(2M))
                int j = lane + (m << 6);
                if (d < db) { db = d; jb = j; }
            }
            for (int s = 1; s < 64; s <<= 1) {     // first-index global argmin
                float od = __shfl_xor(db, s);
                int oj = __shfl_xor(jb, s);
                if ((od < db) || (od == db && oj < jb)) { db = od; jb = oj; }
            }
            float q = cbT[jb * 64 + lane];          // coalesced row gather
            out[(size_t)row * D + lane] = q;
            float e = q - xr[lane];
            wloss += e * e;
        }
    }
    #pragma unroll
    for (int off = 32; off > 0; off >>= 1) wloss += __shfl_down(wloss, off);
    if (lane == 0) wavesum[w] = wloss;
    __syncthreads();
    if (tid == 0) {
        double tot = (double)wavesum[0] + (double)wavesum[1]
                   + (double)wavesum[2] + (double)wavesum[3];
        if (tot != 0.0) atomicAdd(loss_acc, tot);
        __threadfence();
        int old = atomicAdd(done, 1);
        if (old == RESCAN_BLOCKS - 1) {            // last block finalizes loss
            double total = atomicAdd(loss_acc, 0.0);
            out[NELEM] = (float)(total * (1.25 / (double)NELEM));
        }
    }
}

extern "C" void kernel_launch(void* const* d_in, const int* in_sizes, int n_in,
                              void* d_out, int out_size, void* d_ws, size_t ws_size,
                              hipStream_t stream) {
    const float* x  = (const float*)d_in[0];   // [32,64,64,64] fp32
    const float* cb = (const float*)d_in[1];   // [64,512] fp32
    float* out = (float*)d_out;                // [8388608] out + [1] loss
    double* loss_acc = (double*)d_ws;
    int* done        = (int*)((char*)d_ws + 8);
    float* Bneg      = (float*)((char*)d_ws + 4096);
    _Float16* gH     = (_Float16*)((char*)d_ws + 8192);
    _Float16* gL     = (_Float16*)((char*)d_ws + 73728);
    unsigned int* bm = (unsigned int*)((char*)d_ws + 139264);
    float* cbT       = (float*)((char*)d_ws + 155648);

    vq_setup<<<64, 512, 0, stream>>>(cb, gH, gL, Bneg, cbT, loss_acc, done);
    vq_main<<<512, 256, 0, stream>>>(x, cbT, gH, gL, Bneg, out, loss_acc, bm);
    vq_rescan<<<RESCAN_BLOCKS, 256, 0, stream>>>(x, cb, cbT, out, loss_acc, done, bm);
}

// Round 9
// 178.940 us; speedup vs baseline: 1.5440x; 1.0314x over previous
//
#include <hip/hip_runtime.h>
#include <math.h>

#define D 64
#define K 512
#define ROWS 131072       // 32*64*64
#define NELEM (ROWS * D)  // 8388608
#define TGAP_CERT 40.0f   // certification bound in acc units (= 7.6e-5 distance)
#define FLAGBIT (1 << 30)

typedef _Float16 half8 __attribute__((ext_vector_type(8)));
typedef float floatx4 __attribute__((ext_vector_type(4)));

// ws layout (bytes):
//   [0,8)            double loss accumulator   (zeroed by vq_setup)
//   [4096,6144)      float Bneg[512] = -0.5 * colnorm * 2^20 (numpy order)
//   [8192,73728)     _Float16 gH[32768]  hi B-fragments (scale 2^12)
//   [73728,139264)   _Float16 gL[32768]  lo B-fragments (residual, scale 2^12)
//   [139264,155648)  uint32 bitmap[4096] flagged-row bitmap
//   [155648,286720)  float cbT[512*64]   transposed codebook (row j contiguous)

// ---------------------------------------------------------------------------
// Setup: fragments + transposed codebook + scaled norms + zero loss.
// frag: half index = (((n>>4)*2 + (k>>5))*64 + ((k>>3)&3)*16 + (n&15))*8 + (k&7)
// ---------------------------------------------------------------------------
__global__ __launch_bounds__(512) void vq_setup(const float* __restrict__ cb,
                                                _Float16* __restrict__ gH,
                                                _Float16* __restrict__ gL,
                                                float* __restrict__ Bneg,
                                                float* __restrict__ cbT,
                                                double* __restrict__ loss) {
    int idx = blockIdx.x * 512 + threadIdx.x;   // 64 blocks x 512 = 32768
    int k = idx >> 9, n = idx & 511;
    float c = cb[idx];
    float t = c * 4096.0f;                      // 2^12, exact
    _Float16 ch = (_Float16)t;
    float r = t - (float)ch;                    // exact residual
    _Float16 cl = (_Float16)r;                  // same 2^12 scale
    int off = (((n >> 4) * 2 + (k >> 5)) * 64 + ((k >> 3) & 3) * 16 + (n & 15)) * 8 + (k & 7);
    gH[off] = ch;
    gL[off] = cl;
    cbT[n * 64 + k] = c;                        // one-time scattered transpose
    if (blockIdx.x == 0) {
#pragma clang fp contract(off)
        int j = threadIdx.x;
        float b = 0.f;
        for (int kk = 0; kk < D; ++kk) { float cc = cb[kk * K + j]; b = b + cc * cc; }
        Bneg[j] = b * -0x1p19f;                 // -B/2 * 2^20, exact pow-2 scale
        if (j == 0) { *loss = 0.0; }
    }
}

// ---------------------------------------------------------------------------
// Main: MFMA filter, 4 waves x 64 rows/wave = 256 rows/block, 512 blocks.
// ---------------------------------------------------------------------------
__global__ __launch_bounds__(256, 2) void vq_main(const float* __restrict__ x,
                                                  const float* __restrict__ cbT,
                                                  const _Float16* __restrict__ gH,
                                                  const _Float16* __restrict__ gL,
                                                  const float* __restrict__ BnegG,
                                                  float* __restrict__ out,
                                                  double* __restrict__ loss_acc,
                                                  unsigned int* __restrict__ bitmap) {
    __shared__ float ldsB[K];              // -B/2 * 2^20
    __shared__ int rowinfo[4][64];
    __shared__ unsigned int flagbits[8];   // 256 rows
    __shared__ float wavesum[4];

    const int tid = threadIdx.x;
    const int lane = tid & 63;
    const int w = tid >> 6;
    const int quad = lane >> 4;
    const int nn = lane & 15;

    ldsB[tid] = BnegG[tid];
    ldsB[tid + 256] = BnegG[tid + 256];
    if (tid < 8) flagbits[tid] = 0;

    const int rowBase = blockIdx.x * 256 + w * 64;

    // A-fragments: lane holds A[m=nn][k=quad*8+j]; hi 2^8, lo residual 2^8
    half8 xh[4][2], xl[4][2];
    #pragma unroll
    for (int tt = 0; tt < 4; ++tt) {
        #pragma unroll
        for (int s = 0; s < 2; ++s) {
            const float* xp = x + (size_t)(rowBase + tt * 16 + nn) * D + s * 32 + quad * 8;
            float4 v0 = *(const float4*)xp;
            float4 v1 = *(const float4*)(xp + 4);
            float vv[8] = {v0.x, v0.y, v0.z, v0.w, v1.x, v1.y, v1.z, v1.w};
            #pragma unroll
            for (int j = 0; j < 8; ++j) {
                float t = vv[j] * 256.0f;        // 2^8, exact
                _Float16 h = (_Float16)t;
                float r = t - (float)h;          // exact residual
                xh[tt][s][j] = h;
                xl[tt][s][j] = (_Float16)r;      // same 2^8 scale
            }
        }
    }
    __syncthreads();

    // best-2 MAX trackers of acc=(M - B/2)*2^20, col packed in low 9 bits
    float M1[4][4], M2[4][4];
    #pragma unroll
    for (int tt = 0; tt < 4; ++tt)
        #pragma unroll
        for (int r = 0; r < 4; ++r) { M1[tt][r] = -INFINITY; M2[tt][r] = -INFINITY; }

    const half8* bHp = (const half8*)gH;
    const half8* bLp = (const half8*)gL;

    half8 bh0 = bHp[lane], bl0 = bLp[lane];
    half8 bh1 = bHp[64 + lane], bl1 = bLp[64 + lane];

    #pragma unroll 2
    for (int t = 0; t < 32; ++t) {
        int tn = (t + 1) & 31;                   // prefetch next K-tile (wraps, harmless)
        half8 nh0 = bHp[(tn * 2 + 0) * 64 + lane];
        half8 nl0 = bLp[(tn * 2 + 0) * 64 + lane];
        half8 nh1 = bHp[(tn * 2 + 1) * 64 + lane];
        half8 nl1 = bLp[(tn * 2 + 1) * 64 + lane];
        float bneg = ldsB[t * 16 + nn];
        unsigned int colbits = (unsigned)(t * 16 + nn);
        #pragma unroll
        for (int tt = 0; tt < 4; ++tt) {
            floatx4 acc = {bneg, bneg, bneg, bneg};
            acc = __builtin_amdgcn_mfma_f32_16x16x32_f16(xh[tt][0], bh0, acc, 0, 0, 0);
            acc = __builtin_amdgcn_mfma_f32_16x16x32_f16(xl[tt][0], bh0, acc, 0, 0, 0);
            acc = __builtin_amdgcn_mfma_f32_16x16x32_f16(xh[tt][0], bl0, acc, 0, 0, 0);
            acc = __builtin_amdgcn_mfma_f32_16x16x32_f16(xh[tt][1], bh1, acc, 0, 0, 0);
            acc = __builtin_amdgcn_mfma_f32_16x16x32_f16(xl[tt][1], bh1, acc, 0, 0, 0);
            acc = __builtin_amdgcn_mfma_f32_16x16x32_f16(xh[tt][1], bl1, acc, 0, 0, 0);
            #pragma unroll
            for (int r = 0; r < 4; ++r) {
                float gq = __uint_as_float((__float_as_uint(acc[r]) & ~511u) | colbits);
                float lo = fminf(M1[tt][r], gq);
                M2[tt][r] = fmaxf(M2[tt][r], lo);
                M1[tt][r] = fmaxf(M1[tt][r], gq);
            }
        }
        bh0 = nh0; bl0 = nl0; bh1 = nh1; bl1 = nl1;
    }

    // merge best-2 across the 16 col-lanes (butterfly over low 4 lane bits)
    #pragma unroll
    for (int dlt = 1; dlt < 16; dlt <<= 1) {
        #pragma unroll
        for (int tt = 0; tt < 4; ++tt)
            #pragma unroll
            for (int r = 0; r < 4; ++r) {
                float o1 = __shfl_xor(M1[tt][r], dlt);
                float o2 = __shfl_xor(M2[tt][r], dlt);
                float lo = fminf(M1[tt][r], o1);
                M1[tt][r] = fmaxf(M1[tt][r], o1);
                M2[tt][r] = fmaxf(fmaxf(M2[tt][r], o2), lo);
            }
    }

    // record results; flagged rows -> LDS bits.
    // Threshold = cert bound + 1022 ulp(M1): covers both candidates' 511-ulp
    // packing perturbation at M1's binade, regardless of |acc| magnitude.
    if (nn == 0) {
        #pragma unroll
        for (int tt = 0; tt < 4; ++tt)
            #pragma unroll
            for (int r = 0; r < 4; ++r) {
                int rl = tt * 16 + quad * 4 + r;               // 0..63
                int col = (int)(__float_as_uint(M1[tt][r]) & 511u);
                float ulp = __uint_as_float(__float_as_uint(M1[tt][r]) & 0x7f800000u) * 0x1p-23f;
                float thr = fmaf(1022.0f, ulp, TGAP_CERT);
                bool flg = (M1[tt][r] - M2[tt][r]) < thr;
                rowinfo[w][rl] = col | (flg ? FLAGBIT : 0);
                if (flg) atomicOr(&flagbits[(w * 64 + rl) >> 5], 1u << ((w * 64 + rl) & 31));
            }
    }
    __syncthreads();
    if (tid < 8) bitmap[blockIdx.x * 8 + tid] = flagbits[tid];

    // coalesced output + loss for certain rows (cbT row-gather, 1KB/instr write)
    float lsum = 0.f;
    #pragma unroll
    for (int tt = 0; tt < 4; ++tt) {
        #pragma unroll
        for (int p = 0; p < 4; ++p) {
            int rl = tt * 16 + p * 4 + quad;
            int info = rowinfo[w][rl];
            if (!(info & FLAGBIT)) {
                int j = info & 511;
                size_t row = (size_t)rowBase + rl;
                float4 qv = *(const float4*)(cbT + j * 64 + nn * 4);
                float4 xv = *(const float4*)(x + row * D + nn * 4);
                float e0 = qv.x - xv.x, e1 = qv.y - xv.y;
                float e2 = qv.z - xv.z, e3 = qv.w - xv.w;
                lsum += e0 * e0 + e1 * e1 + e2 * e2 + e3 * e3;
                *(float4*)(out + row * D + nn * 4) = qv;
            }
        }
    }
    #pragma unroll
    for (int off = 32; off > 0; off >>= 1) lsum += __shfl_down(lsum, off);
    if (lane == 0) wavesum[w] = lsum;
    __syncthreads();
    if (tid == 0) {
        double tot = (double)wavesum[0] + (double)wavesum[1]
                   + (double)wavesum[2] + (double)wavesum[3];
        atomicAdd(loss_acc, tot);
    }
}

// ---------------------------------------------------------------------------
// Rescan: exact numpy-order pipeline for flagged rows (bitwise R2 path).
// One wave per 64-row span. NO threadfence / done counter (R8 lesson:
// per-block agent fences cost ~50us in L2 writebacks).
// ---------------------------------------------------------------------------
__global__ __launch_bounds__(256) void vq_rescan(const float* __restrict__ x,
                                                 const float* __restrict__ cb,
                                                 const float* __restrict__ cbT,
                                                 float* __restrict__ out,
                                                 double* __restrict__ loss_acc,
                                                 const unsigned int* __restrict__ bitmap) {
#pragma clang fp contract(off)
    __shared__ float wavesum[4];
    const int tid = threadIdx.x;
    const int lane = tid & 63;
    const int w = tid >> 6;
    const int gwave = blockIdx.x * 4 + w;      // 0..2047

    unsigned int w0 = bitmap[gwave * 2 + 0];
    unsigned int w1 = bitmap[gwave * 2 + 1];
    unsigned long long mask = ((unsigned long long)w1 << 32) | w0;
    float wloss = 0.f;
    if (mask) {
        // numpy-order column norms for lane's 8 columns (hoisted)
        float bn[8];
        #pragma unroll
        for (int m = 0; m < 8; ++m) bn[m] = 0.f;
        for (int k = 0; k < D; ++k) {
            const float* crow = cb + k * K + lane;
            #pragma unroll
            for (int m = 0; m < 8; ++m) {
                float c = crow[m * 64];
                bn[m] = bn[m] + c * c;
            }
        }
        while (mask) {
            int b = __builtin_ctzll(mask);
            mask &= mask - 1;
            int row = gwave * 64 + b;
            const float* xr = x + (size_t)row * D;
            // A = np.sum(x**2, axis=1): pairwise n=64 emulation
            float A0;
            {
                float rr[8];
                #pragma unroll
                for (int l = 0; l < 8; ++l) rr[l] = xr[l] * xr[l];
                #pragma unroll
                for (int m = 1; m < 8; ++m)
                    #pragma unroll
                    for (int l = 0; l < 8; ++l) {
                        float q = xr[8 * m + l] * xr[8 * m + l];
                        rr[l] = rr[l] + q;
                    }
                A0 = ((rr[0] + rr[1]) + (rr[2] + rr[3])) + ((rr[4] + rr[5]) + (rr[6] + rr[7]));
            }
            float a[8];
            #pragma unroll
            for (int m = 0; m < 8; ++m) a[m] = 0.f;
            for (int k = 0; k < D; ++k) {
                float xk = xr[k];
                const float* crow = cb + k * K + lane;
                #pragma unroll
                for (int m = 0; m < 8; ++m)
                    a[m] = fmaf(xk, crow[m * 64], a[m]);   // sequential-k fma chain
            }
            float db = INFINITY; int jb = 0x7fffffff;
            #pragma unroll
            for (int m = 0; m < 8; ++m) {
                float s = A0 + bn[m];
                float t2 = 2.0f * a[m];
                float d = s - t2;                  // fl(fl(A+B) - fl(2M))
                int j = lane + (m << 6);
                if (d < db) { db = d; jb = j; }
            }
            for (int s = 1; s < 64; s <<= 1) {     // first-index global argmin
                float od = __shfl_xor(db, s);
                int oj = __shfl_xor(jb, s);
                if ((od < db) || (od == db && oj < jb)) { db = od; jb = oj; }
            }
            float q = cbT[jb * 64 + lane];          // coalesced row gather
            out[(size_t)row * D + lane] = q;
            float e = q - xr[lane];
            wloss += e * e;
        }
    }
    #pragma unroll
    for (int off = 32; off > 0; off >>= 1) wloss += __shfl_down(wloss, off);
    if (lane == 0) wavesum[w] = wloss;
    __syncthreads();
    if (tid == 0) {
        double tot = (double)wavesum[0] + (double)wavesum[1]
                   + (double)wavesum[2] + (double)wavesum[3];
        if (tot != 0.0) atomicAdd(loss_acc, tot);
    }
}

__global__ void vq_finalize(const double* __restrict__ acc, float* __restrict__ out) {
    // loss = (1 + beta) * mean((q - x)^2), beta = 0.25
    out[NELEM] = (float)(acc[0] * (1.25 / (double)NELEM));
}

extern "C" void kernel_launch(void* const* d_in, const int* in_sizes, int n_in,
                              void* d_out, int out_size, void* d_ws, size_t ws_size,
                              hipStream_t stream) {
    const float* x  = (const float*)d_in[0];   // [32,64,64,64] fp32
    const float* cb = (const float*)d_in[1];   // [64,512] fp32
    float* out = (float*)d_out;                // [8388608] out + [1] loss
    double* loss_acc = (double*)d_ws;
    float* Bneg      = (float*)((char*)d_ws + 4096);
    _Float16* gH     = (_Float16*)((char*)d_ws + 8192);
    _Float16* gL     = (_Float16*)((char*)d_ws + 73728);
    unsigned int* bm = (unsigned int*)((char*)d_ws + 139264);
    float* cbT       = (float*)((char*)d_ws + 155648);

    vq_setup<<<64, 512, 0, stream>>>(cb, gH, gL, Bneg, cbT, loss_acc);
    vq_main<<<512, 256, 0, stream>>>(x, cbT, gH, gL, Bneg, out, loss_acc, bm);
    vq_rescan<<<512, 256, 0, stream>>>(x, cb, cbT, out, loss_acc, bm);
    vq_finalize<<<1, 1, 0, stream>>>(loss_acc, out);
}

// Round 10
// 178.615 us; speedup vs baseline: 1.5468x; 1.0018x over previous
//
#include <hip/hip_runtime.h>
#include <math.h>

#define D 64
#define K 512
#define ROWS 131072       // 32*64*64
#define NELEM (ROWS * D)  // 8388608
#define TGAP_CERT 40.0f   // certification bound in acc units (= 7.6e-5 distance)
#define FLAGBIT (1 << 30)

typedef _Float16 half8 __attribute__((ext_vector_type(8)));
typedef float floatx4 __attribute__((ext_vector_type(4)));

// ws layout (bytes):
//   [0,8)            double loss accumulator   (zeroed by vq_setup)
//   [4096,6144)      float Bneg[512] = -0.5 * colnorm * 2^20 (numpy order)
//   [8192,73728)     _Float16 gH[32768]  hi B-fragments (scale 2^12)
//   [73728,139264)   _Float16 gL[32768]  lo B-fragments (residual, scale 2^12)
//   [139264,155648)  uint32 bitmap[4096] flagged-row bitmap
//   [155648,286720)  float cbT[512*64]   transposed codebook (row j contiguous)

// ---------------------------------------------------------------------------
// Setup: fragments + transposed codebook + scaled norms + zero loss.
// frag: half index = (((n>>4)*2 + (k>>5))*64 + ((k>>3)&3)*16 + (n&15))*8 + (k&7)
// ---------------------------------------------------------------------------
__global__ __launch_bounds__(512) void vq_setup(const float* __restrict__ cb,
                                                _Float16* __restrict__ gH,
                                                _Float16* __restrict__ gL,
                                                float* __restrict__ Bneg,
                                                float* __restrict__ cbT,
                                                double* __restrict__ loss) {
    int idx = blockIdx.x * 512 + threadIdx.x;   // 64 blocks x 512 = 32768
    int k = idx >> 9, n = idx & 511;
    float c = cb[idx];
    float t = c * 4096.0f;                      // 2^12, exact
    _Float16 ch = (_Float16)t;
    float r = t - (float)ch;                    // exact residual
    _Float16 cl = (_Float16)r;                  // same 2^12 scale
    int off = (((n >> 4) * 2 + (k >> 5)) * 64 + ((k >> 3) & 3) * 16 + (n & 15)) * 8 + (k & 7);
    gH[off] = ch;
    gL[off] = cl;
    cbT[n * 64 + k] = c;                        // one-time scattered transpose
    if (blockIdx.x == 0) {
#pragma clang fp contract(off)
        int j = threadIdx.x;
        float b = 0.f;
        for (int kk = 0; kk < D; ++kk) { float cc = cb[kk * K + j]; b = b + cc * cc; }
        Bneg[j] = b * -0x1p19f;                 // -B/2 * 2^20, exact pow-2 scale
        if (j == 0) { *loss = 0.0; }
    }
}

// ---------------------------------------------------------------------------
// Main: MFMA filter, 4 waves x 64 rows/wave = 256 rows/block, 512 blocks.
// ---------------------------------------------------------------------------
__global__ __launch_bounds__(256, 2) void vq_main(const float* __restrict__ x,
                                                  const float* __restrict__ cbT,
                                                  const _Float16* __restrict__ gH,
                                                  const _Float16* __restrict__ gL,
                                                  const float* __restrict__ BnegG,
                                                  float* __restrict__ out,
                                                  double* __restrict__ loss_acc,
                                                  unsigned int* __restrict__ bitmap) {
    __shared__ float ldsB[K];              // -B/2 * 2^20
    __shared__ int rowinfo[4][64];
    __shared__ unsigned int flagbits[8];   // 256 rows
    __shared__ float wavesum[4];

    const int tid = threadIdx.x;
    const int lane = tid & 63;
    const int w = tid >> 6;
    const int quad = lane >> 4;
    const int nn = lane & 15;

    ldsB[tid] = BnegG[tid];
    ldsB[tid + 256] = BnegG[tid + 256];
    if (tid < 8) flagbits[tid] = 0;

    const int rowBase = blockIdx.x * 256 + w * 64;

    // A-fragments: lane holds A[m=nn][k=quad*8+j]; hi 2^8, lo residual 2^8
    half8 xh[4][2], xl[4][2];
    #pragma unroll
    for (int tt = 0; tt < 4; ++tt) {
        #pragma unroll
        for (int s = 0; s < 2; ++s) {
            const float* xp = x + (size_t)(rowBase + tt * 16 + nn) * D + s * 32 + quad * 8;
            float4 v0 = *(const float4*)xp;
            float4 v1 = *(const float4*)(xp + 4);
            float vv[8] = {v0.x, v0.y, v0.z, v0.w, v1.x, v1.y, v1.z, v1.w};
            #pragma unroll
            for (int j = 0; j < 8; ++j) {
                float t = vv[j] * 256.0f;        // 2^8, exact
                _Float16 h = (_Float16)t;
                float r = t - (float)h;          // exact residual
                xh[tt][s][j] = h;
                xl[tt][s][j] = (_Float16)r;      // same 2^8 scale
            }
        }
    }
    __syncthreads();

    // best-2 MAX trackers of acc=(M - B/2)*2^20, col packed in low 9 bits
    float M1[4][4], M2[4][4];
    #pragma unroll
    for (int tt = 0; tt < 4; ++tt)
        #pragma unroll
        for (int r = 0; r < 4; ++r) { M1[tt][r] = -INFINITY; M2[tt][r] = -INFINITY; }

    const half8* bHp = (const half8*)gH;
    const half8* bLp = (const half8*)gL;

    half8 bh0 = bHp[lane], bl0 = bLp[lane];
    half8 bh1 = bHp[64 + lane], bl1 = bLp[64 + lane];

    #pragma unroll 2
    for (int t = 0; t < 32; ++t) {
        int tn = (t + 1) & 31;                   // prefetch next K-tile (wraps, harmless)
        half8 nh0 = bHp[(tn * 2 + 0) * 64 + lane];
        half8 nl0 = bLp[(tn * 2 + 0) * 64 + lane];
        half8 nh1 = bHp[(tn * 2 + 1) * 64 + lane];
        half8 nl1 = bLp[(tn * 2 + 1) * 64 + lane];
        float bneg = ldsB[t * 16 + nn];
        unsigned int colbits = (unsigned)(t * 16 + nn);
        #pragma unroll
        for (int tt = 0; tt < 4; ++tt) {
            floatx4 acc = {bneg, bneg, bneg, bneg};
            acc = __builtin_amdgcn_mfma_f32_16x16x32_f16(xh[tt][0], bh0, acc, 0, 0, 0);
            acc = __builtin_amdgcn_mfma_f32_16x16x32_f16(xl[tt][0], bh0, acc, 0, 0, 0);
            acc = __builtin_amdgcn_mfma_f32_16x16x32_f16(xh[tt][0], bl0, acc, 0, 0, 0);
            acc = __builtin_amdgcn_mfma_f32_16x16x32_f16(xh[tt][1], bh1, acc, 0, 0, 0);
            acc = __builtin_amdgcn_mfma_f32_16x16x32_f16(xl[tt][1], bh1, acc, 0, 0, 0);
            acc = __builtin_amdgcn_mfma_f32_16x16x32_f16(xh[tt][1], bl1, acc, 0, 0, 0);
            #pragma unroll
            for (int r = 0; r < 4; ++r) {
                float gq = __uint_as_float((__float_as_uint(acc[r]) & ~511u) | colbits);
                float lo = fminf(M1[tt][r], gq);
                M2[tt][r] = fmaxf(M2[tt][r], lo);
                M1[tt][r] = fmaxf(M1[tt][r], gq);
            }
        }
        bh0 = nh0; bl0 = nl0; bh1 = nh1; bl1 = nl1;
    }

    // merge best-2 across the 16 col-lanes (butterfly over low 4 lane bits)
    #pragma unroll
    for (int dlt = 1; dlt < 16; dlt <<= 1) {
        #pragma unroll
        for (int tt = 0; tt < 4; ++tt)
            #pragma unroll
            for (int r = 0; r < 4; ++r) {
                float o1 = __shfl_xor(M1[tt][r], dlt);
                float o2 = __shfl_xor(M2[tt][r], dlt);
                float lo = fminf(M1[tt][r], o1);
                M1[tt][r] = fmaxf(M1[tt][r], o1);
                M2[tt][r] = fmaxf(fmaxf(M2[tt][r], o2), lo);
            }
    }

    // record results; flagged rows -> LDS bits.
    // Threshold = cert bound + 1022 ulp(M1): covers both candidates' 511-ulp
    // packing perturbation at M1's binade, regardless of |acc| magnitude.
    if (nn == 0) {
        #pragma unroll
        for (int tt = 0; tt < 4; ++tt)
            #pragma unroll
            for (int r = 0; r < 4; ++r) {
                int rl = tt * 16 + quad * 4 + r;               // 0..63
                int col = (int)(__float_as_uint(M1[tt][r]) & 511u);
                float ulp = __uint_as_float(__float_as_uint(M1[tt][r]) & 0x7f800000u) * 0x1p-23f;
                float thr = fmaf(1022.0f, ulp, TGAP_CERT);
                bool flg = (M1[tt][r] - M2[tt][r]) < thr;
                rowinfo[w][rl] = col | (flg ? FLAGBIT : 0);
                if (flg) atomicOr(&flagbits[(w * 64 + rl) >> 5], 1u << ((w * 64 + rl) & 31));
            }
    }
    __syncthreads();
    if (tid < 8) bitmap[blockIdx.x * 8 + tid] = flagbits[tid];

    // coalesced output + loss for certain rows (cbT row-gather, 1KB/instr write)
    float lsum = 0.f;
    #pragma unroll
    for (int tt = 0; tt < 4; ++tt) {
        #pragma unroll
        for (int p = 0; p < 4; ++p) {
            int rl = tt * 16 + p * 4 + quad;
            int info = rowinfo[w][rl];
            if (!(info & FLAGBIT)) {
                int j = info & 511;
                size_t row = (size_t)rowBase + rl;
                float4 qv = *(const float4*)(cbT + j * 64 + nn * 4);
                float4 xv = *(const float4*)(x + row * D + nn * 4);
                float e0 = qv.x - xv.x, e1 = qv.y - xv.y;
                float e2 = qv.z - xv.z, e3 = qv.w - xv.w;
                lsum += e0 * e0 + e1 * e1 + e2 * e2 + e3 * e3;
                *(float4*)(out + row * D + nn * 4) = qv;
            }
        }
    }
    #pragma unroll
    for (int off = 32; off > 0; off >>= 1) lsum += __shfl_down(lsum, off);
    if (lane == 0) wavesum[w] = lsum;
    __syncthreads();
    if (tid == 0) {
        double tot = (double)wavesum[0] + (double)wavesum[1]
                   + (double)wavesum[2] + (double)wavesum[3];
        atomicAdd(loss_acc, tot);
    }
}

// ---------------------------------------------------------------------------
// Rescan: exact numpy-order pipeline for flagged rows (bitwise R2 path).
// One wave per 64-row span. k-loops unrolled x8 so loads pipeline (R9 lesson:
// un-unrolled loop exposes one L2 round-trip per k iteration, ~5us/row).
// Unrolling preserves the fmaf dependency chains -> bit-identical results.
// ---------------------------------------------------------------------------
__global__ __launch_bounds__(256) void vq_rescan(const float* __restrict__ x,
                                                 const float* __restrict__ cb,
                                                 const float* __restrict__ cbT,
                                                 float* __restrict__ out,
                                                 double* __restrict__ loss_acc,
                                                 const unsigned int* __restrict__ bitmap) {
#pragma clang fp contract(off)
    __shared__ float wavesum[4];
    const int tid = threadIdx.x;
    const int lane = tid & 63;
    const int w = tid >> 6;
    const int gwave = blockIdx.x * 4 + w;      // 0..2047

    unsigned int w0 = bitmap[gwave * 2 + 0];
    unsigned int w1 = bitmap[gwave * 2 + 1];
    unsigned long long mask = ((unsigned long long)w1 << 32) | w0;
    float wloss = 0.f;
    if (mask) {
        // numpy-order column norms for lane's 8 columns (hoisted)
        float bn[8];
        #pragma unroll
        for (int m = 0; m < 8; ++m) bn[m] = 0.f;
        #pragma unroll 8
        for (int k = 0; k < D; ++k) {
            const float* crow = cb + k * K + lane;
            #pragma unroll
            for (int m = 0; m < 8; ++m) {
                float c = crow[m * 64];
                bn[m] = bn[m] + c * c;
            }
        }
        while (mask) {
            int b = __builtin_ctzll(mask);
            mask &= mask - 1;
            int row = gwave * 64 + b;
            const float* xr = x + (size_t)row * D;
            // A = np.sum(x**2, axis=1): pairwise n=64 emulation
            float A0;
            {
                float rr[8];
                #pragma unroll
                for (int l = 0; l < 8; ++l) rr[l] = xr[l] * xr[l];
                #pragma unroll
                for (int m = 1; m < 8; ++m)
                    #pragma unroll
                    for (int l = 0; l < 8; ++l) {
                        float q = xr[8 * m + l] * xr[8 * m + l];
                        rr[l] = rr[l] + q;
                    }
                A0 = ((rr[0] + rr[1]) + (rr[2] + rr[3])) + ((rr[4] + rr[5]) + (rr[6] + rr[7]));
            }
            float a[8];
            #pragma unroll
            for (int m = 0; m < 8; ++m) a[m] = 0.f;
            #pragma unroll 8
            for (int k = 0; k < D; ++k) {
                float xk = xr[k];
                const float* crow = cb + k * K + lane;
                #pragma unroll
                for (int m = 0; m < 8; ++m)
                    a[m] = fmaf(xk, crow[m * 64], a[m]);   // sequential-k fma chain
            }
            float db = INFINITY; int jb = 0x7fffffff;
            #pragma unroll
            for (int m = 0; m < 8; ++m) {
                float s = A0 + bn[m];
                float t2 = 2.0f * a[m];
                float d = s - t2;                  // fl(fl(A+B) - fl(2M))
                int j = lane + (m << 6);
                if (d < db) { db = d; jb = j; }
            }
            for (int s = 1; s < 64; s <<= 1) {     // first-index global argmin
                float od = __shfl_xor(db, s);
                int oj = __shfl_xor(jb, s);
                if ((od < db) || (od == db && oj < jb)) { db = od; jb = oj; }
            }
            float q = cbT[jb * 64 + lane];          // coalesced row gather
            out[(size_t)row * D + lane] = q;
            float e = q - xr[lane];
            wloss += e * e;
        }
    }
    #pragma unroll
    for (int off = 32; off > 0; off >>= 1) wloss += __shfl_down(wloss, off);
    if (lane == 0) wavesum[w] = wloss;
    __syncthreads();
    if (tid == 0) {
        double tot = (double)wavesum[0] + (double)wavesum[1]
                   + (double)wavesum[2] + (double)wavesum[3];
        if (tot != 0.0) atomicAdd(loss_acc, tot);
    }
}

__global__ void vq_finalize(const double* __restrict__ acc, float* __restrict__ out) {
    // loss = (1 + beta) * mean((q - x)^2), beta = 0.25
    out[NELEM] = (float)(acc[0] * (1.25 / (double)NELEM));
}

extern "C" void kernel_launch(void* const* d_in, const int* in_sizes, int n_in,
                              void* d_out, int out_size, void* d_ws, size_t ws_size,
                              hipStream_t stream) {
    const float* x  = (const float*)d_in[0];   // [32,64,64,64] fp32
    const float* cb = (const float*)d_in[1];   // [64,512] fp32
    float* out = (float*)d_out;                // [8388608] out + [1] loss
    double* loss_acc = (double*)d_ws;
    float* Bneg      = (float*)((char*)d_ws + 4096);
    _Float16* gH     = (_Float16*)((char*)d_ws + 8192);
    _Float16* gL     = (_Float16*)((char*)d_ws + 73728);
    unsigned int* bm = (unsigned int*)((char*)d_ws + 139264);
    float* cbT       = (float*)((char*)d_ws + 155648);

    vq_setup<<<64, 512, 0, stream>>>(cb, gH, gL, Bneg, cbT, loss_acc);
    vq_main<<<512, 256, 0, stream>>>(x, cbT, gH, gL, Bneg, out, loss_acc, bm);
    vq_rescan<<<512, 256, 0, stream>>>(x, cb, cbT, out, loss_acc, bm);
    vq_finalize<<<1, 1, 0, stream>>>(loss_acc, out);
}